// Round 6
// baseline (152.148 us; speedup 1.0000x reference)
//
#include <hip/hip_runtime.h>

#define IMG_W 512
#define IMG_H 512
#define BATCH 64
#define ROWS_PER_WAVE 4
#define SLABS (IMG_H / ROWS_PER_WAVE)        // 128 slabs/image
#define NBLOCKS (BATCH * SLABS)              // 8192 blocks, 1 wave each
#define NPIX (BATCH * IMG_W * IMG_H)

__device__ __forceinline__ float fast_sqrtf(float x) {
    return __builtin_amdgcn_sqrtf(x);
}

// Row-streaming Sobel, one wave per block. Lane = 8-px strip (64*8=512=row).
// R5 lessons: warm-L3 replay still took 45us -> duration is latency-bound,
// not traffic-bound; exact-capacity grids average only ~5 resident waves/CU.
// Fix: (1) 4 rows/wave -> 8192 blocks (2x+ oversubscription), (2) 5 row
// buffers so the prologue puts 20KB/wave in flight and steady-state reissue
// distance is 2 compute steps. Buffers are named float4 regs (no copies),
// all indices compile-time constants (R3 spill lesson).
__global__ __launch_bounds__(64) void sobel_loss_kernel(
    const float* __restrict__ yp, const float* __restrict__ yt,
    float* __restrict__ bsums)
{
    const int lane = threadIdx.x;            // block == one wave
    const int bid  = blockIdx.x;
    const int b    = bid >> 7;               // image index (128 slabs/image)
    const int slab = bid & (SLABS - 1);
    const int y0   = slab * ROWS_PER_WAVE;
    const int x0   = lane << 3;              // cols x0..x0+7

    const float* __restrict__ imgp = yp + (size_t)b * (IMG_W * IMG_H);
    const float* __restrict__ imgt = yt + (size_t)b * (IMG_W * IMG_H);

    // 5 row buffers x 2 images: A=cols x0..x0+3, B=cols x0+4..x0+7,
    // l/r = halo scalars (cols x0-1, x0+8) filled by HALO via shfl.
    float4 A0p, B0p, A0t, B0t, A1p, B1p, A1t, B1t, A2p, B2p, A2t, B2t;
    float4 A3p, B3p, A3t, B3t, A4p, B4p, A4t, B4t;
    float  l0p, r0p, l0t, r0t, l1p, r1p, l1t, r1t, l2p, r2p, l2t, r2t;
    float  l3p, r3p, l3t, r3t, l4p, r4p, l4t, r4t;

    // Issue row Y's 4 float4 loads into buffer S. Wave-uniform bounds branch.
#define ISSUE(S, Y)                                                            \
    do {                                                                       \
        int yy = (Y);                                                          \
        if (yy >= 0 && yy < IMG_H) {                                           \
            const float* rp = imgp + (size_t)yy * IMG_W + x0;                  \
            const float* rt = imgt + (size_t)yy * IMG_W + x0;                  \
            A##S##p = *(const float4*)rp;                                      \
            B##S##p = *(const float4*)(rp + 4);                                \
            A##S##t = *(const float4*)rt;                                      \
            B##S##t = *(const float4*)(rt + 4);                                \
        } else {                                                               \
            A##S##p = {0.f, 0.f, 0.f, 0.f}; B##S##p = {0.f, 0.f, 0.f, 0.f};   \
            A##S##t = {0.f, 0.f, 0.f, 0.f}; B##S##t = {0.f, 0.f, 0.f, 0.f};   \
        }                                                                      \
    } while (0)

    // Fill halo scalars of buffer S from neighbor lanes (vmcnt wait lands
    // here); image edge -> 0 ('SAME' zero padding).
#define HALO(S)                                                                \
    do {                                                                       \
        l##S##p = __shfl_up(B##S##p.w, 1, 64);                                 \
        r##S##p = __shfl_down(A##S##p.x, 1, 64);                               \
        l##S##t = __shfl_up(B##S##t.w, 1, 64);                                 \
        r##S##t = __shfl_down(A##S##t.x, 1, 64);                               \
        if (lane == 0)  { l##S##p = 0.f; l##S##t = 0.f; }                      \
        if (lane == 63) { r##S##p = 0.f; r##S##t = 0.f; }                      \
    } while (0)

    // Materialize buffer R as a 10-wide const array (SSA'd away, no copies).
#define ROW_ARR(NAME, R, IMG)                                                  \
    const float NAME[10] = { l##R##IMG,                                        \
        A##R##IMG.x, A##R##IMG.y, A##R##IMG.z, A##R##IMG.w,                    \
        B##R##IMG.x, B##R##IMG.y, B##R##IMG.z, B##R##IMG.w, r##R##IMG };

    float lsum = 0.f;

    // One output row: Ra = y-1, Rb = y, Rc = y+1 (all assembled).
#define COMPUTE(Ra, Rb, Rc)                                                    \
    do {                                                                       \
        ROW_ARR(w0p, Ra, p) ROW_ARR(w1p, Rb, p) ROW_ARR(w2p, Rc, p)            \
        ROW_ARR(w0t, Ra, t) ROW_ARR(w1t, Rb, t) ROW_ARR(w2t, Rc, t)            \
        float cp[10], ct[10];                                                  \
        _Pragma("unroll")                                                      \
        for (int k = 0; k < 10; ++k) {                                         \
            cp[k] = fmaf(2.f, w1p[k], w0p[k]) + w2p[k];                        \
            ct[k] = fmaf(2.f, w1t[k], w0t[k]) + w2t[k];                        \
        }                                                                      \
        _Pragma("unroll")                                                      \
        for (int j = 0; j < 8; ++j) {                                          \
            float tp  = fmaf(2.f, w2p[j + 1], w2p[j]) + w2p[j + 2];            \
            float bp_ = fmaf(2.f, w0p[j + 1], w0p[j]) + w0p[j + 2];            \
            float ghp = tp - bp_;                                              \
            float gvp = cp[j + 2] - cp[j];                                     \
            float magp = fast_sqrtf(fmaf(gvp, gvp, fmaf(ghp, ghp, 1e-18f)));   \
            float tt  = fmaf(2.f, w2t[j + 1], w2t[j]) + w2t[j + 2];            \
            float bt_ = fmaf(2.f, w0t[j + 1], w0t[j]) + w0t[j + 2];            \
            float ght = tt - bt_;                                              \
            float gvt = ct[j + 2] - ct[j];                                     \
            float magt = fast_sqrtf(fmaf(gvt, gvt, fmaf(ght, ght, 1e-18f)));   \
            lsum += fabsf(magt - magp); /* == sqrt(d^2+eps)*(d^2!=0) */        \
        }                                                                      \
    } while (0)

    // Prologue: all 5 window rows in flight (20 KB/wave).
    ISSUE(0, y0 - 1);
    ISSUE(1, y0);
    ISSUE(2, y0 + 1);
    ISSUE(3, y0 + 2);
    ISSUE(4, y0 + 3);

    HALO(0); HALO(1); HALO(2);
    COMPUTE(0, 1, 2);                 // out y0
    ISSUE(0, y0 + 4);                 // reissue freed buffer, distance 2
    HALO(3); COMPUTE(1, 2, 3);        // out y0+1
    HALO(4); COMPUTE(2, 3, 4);        // out y0+2
    HALO(0); COMPUTE(3, 4, 0);        // out y0+3

#undef ISSUE
#undef HALO
#undef ROW_ARR
#undef COMPUTE

    // ---- Wave reduction (block == wave) ----
#pragma unroll
    for (int off = 32; off > 0; off >>= 1)
        lsum += __shfl_down(lsum, off, 64);
    if (lane == 0)
        bsums[bid] = lsum;
}

__global__ __launch_bounds__(256) void reduce_final(
    const float* __restrict__ bsums, float* __restrict__ out)
{
    __shared__ float wred[4];
    const int tid = threadIdx.x;
    float s = 0.f;
    for (int i = tid; i < NBLOCKS; i += 256) s += bsums[i];
#pragma unroll
    for (int off = 32; off > 0; off >>= 1)
        s += __shfl_down(s, off, 64);
    if ((tid & 63) == 0) wred[tid >> 6] = s;
    __syncthreads();
    if (tid == 0)
        out[0] = (wred[0] + wred[1] + wred[2] + wred[3]) * (1.0f / (float)NPIX);
}

extern "C" void kernel_launch(void* const* d_in, const int* in_sizes, int n_in,
                              void* d_out, int out_size, void* d_ws, size_t ws_size,
                              hipStream_t stream) {
    const float* yp = (const float*)d_in[0];
    const float* yt = (const float*)d_in[1];
    float* out = (float*)d_out;

    float* bsums = (float*)d_ws;   // 32 KB of workspace
    sobel_loss_kernel<<<NBLOCKS, 64, 0, stream>>>(yp, yt, bsums);
    reduce_final<<<1, 256, 0, stream>>>(bsums, out);
}